// Round 19
// baseline (29.273 us; speedup 1.0000x reference)
//
#include <hip/hip_runtime.h>
#include <math.h>
#include <stdint.h>

#define NHEAD 4
#define DD 100
#define NW 39            // word rows
#define BLOCK 256

typedef float v2f __attribute__((ext_vector_type(2)));
typedef __attribute__((address_space(3))) uint32_t lds_t;
typedef const __attribute__((address_space(1))) uint32_t glb_t;

__global__ __launch_bounds__(BLOCK, 6) void ts_enc(
    const float* __restrict__ x,       // [4800][40][100]
    const float* __restrict__ w_att,   // [4][100]
    const float* __restrict__ b_att,   // [4][100]
    float* __restrict__ out)           // [4800][400]
{
    __shared__ float tile[40 * DD];    // 16 KB: row0 = type_emb, rows 1..39 = words

    const int tid  = threadIdx.x;
    const int wv   = __builtin_amdgcn_readfirstlane(tid >> 6);   // wave = head
    const int lane = tid & 63;
    const float* xsite = x + (size_t)blockIdx.x * (40 * DD);

    // ---- stage site tile: async global->LDS, 16 B/lane, NT policy (aux=2):
    //      x lines are single-use per replay — do not let them own L2 ----
    #pragma unroll
    for (int i = 0; i < 4; ++i) {
        const int cf = i * BLOCK + tid;
        if (cf < 1000) {
            glb_t* g = (glb_t*)(xsite + cf * 4);
            lds_t* l = (lds_t*)(tile + (i * BLOCK + wv * 64) * 4);
            __builtin_amdgcn_global_load_lds(g, l, 16, 0, /*aux=NT*/2);
        }
    }
    __syncthreads();                   // the ONLY barrier in the kernel

    // ---- Phase A: wave = head wv; lane = n; all 25 chunks in-wave ----
    // leaky(p) = max(p, 0.3p); te/w/b wave-uniform -> scalar pipe (K$-hot)
    const bool act  = lane < NW;
    const int  nrow = act ? lane : NW - 1;          // clamp idle lanes
    const float* wrow = tile + (1 + nrow) * DD;
    const float* wh = w_att + wv * DD;
    const float* bh = b_att + wv * DD;

    v2f accA = {0.f, 0.f}, accB = {0.f, 0.f};
    #pragma unroll
    for (int c = 0; c < 25; ++c) {
        const v2f x01 = *(const v2f*)(wrow + c * 4);     // ds_read_b64
        const v2f x23 = *(const v2f*)(wrow + c * 4 + 2); // ds_read_b64
        const v2f t01 = *(const v2f*)(xsite + c * 4);    // s_load (uniform)
        const v2f t23 = *(const v2f*)(xsite + c * 4 + 2);
        const v2f w01 = *(const v2f*)(wh + c * 4);       // s_load (uniform)
        const v2f w23 = *(const v2f*)(wh + c * 4 + 2);
        const v2f b01 = *(const v2f*)(bh + c * 4);
        const v2f b23 = *(const v2f*)(bh + c * 4 + 2);
        const v2f p01 = x01 * w01 + b01;
        const v2f p23 = x23 * w23 + b23;
        const v2f l01 = __builtin_elementwise_max(p01, 0.3f * p01);
        const v2f l23 = __builtin_elementwise_max(p23, 0.3f * p23);
        accA = t01 * l01 + accA;
        accB = t23 * l23 + accB;
    }
    const float sc = (accA.x + accA.y) + (accB.x + accB.y);

    // ---- Phase B: raw exp (reference computes exp without max-subtract) ----
    const float e = act ? __expf(sc) : 0.f;         // lane n holds e[head=wv][n]

    // ---- Phase C: lane = d-pair (50 active); att via v_readlane; denominator
    //      folded into the same loop; normalize at store ----
    const int l2 = lane < 50 ? lane : 49;           // clamp idle lanes
    const float* wb = tile + DD + l2 * 2;
    v2f o = {0.f, 0.f};
    float s = 0.f;
    #pragma unroll
    for (int n = 0; n < NW; ++n) {
        const float en = __builtin_bit_cast(float,
            __builtin_amdgcn_readlane(__builtin_bit_cast(int, e), n));
        const v2f wd = *(const v2f*)(wb + n * DD);  // 50-lane b64, ~2-way banks
        o = en * wd + o;                            // v_pk_fma
        s += en;
    }
    const float r = 1.f / s;                        // all-zero site: s=39, o=0 ✓
    if (lane < 50) {
        const v2f q = { o.x * r, o.y * r };
        __builtin_nontemporal_store(q,
            (v2f*)(out + (size_t)blockIdx.x * (NHEAD * DD) + wv * DD + lane * 2));
    }
}

extern "C" void kernel_launch(void* const* d_in, const int* in_sizes, int n_in,
                              void* d_out, int out_size, void* d_ws, size_t ws_size,
                              hipStream_t stream) {
    const float* x     = (const float*)d_in[0];
    const float* w_att = (const float*)d_in[1];
    const float* b_att = (const float*)d_in[2];
    float* out = (float*)d_out;

    const int sites = 8 * 30 * 20;   // 4800
    ts_enc<<<sites, BLOCK, 0, stream>>>(x, w_att, b_att, out);
}